// Round 13
// baseline (698.605 us; speedup 1.0000x reference)
//
#include <hip/hip_runtime.h>
#include <stdint.h>

#define NN 20000
#define EE 320000
#define FF 64
#define ROW 128              // B*F
#define KTOP 160000
#define NEG_SLOPE 0.2f
#define LN_EPS 1e-5f
#define H16BINS 16384        // (u>>12) - (120<<11), clamped: covers alpha in [2^-7, 1]
#define HBASE (120 << 11)
#define CCAP 16384
#define ASTR 136             // bf16 stride for MFMA LDS tiles (16B-aligned frag reads)

typedef __attribute__((ext_vector_type(8))) short short8;
typedef __attribute__((ext_vector_type(4))) float f32x4;

__device__ __forceinline__ unsigned int bin_of(unsigned int u) {
  int b = (int)(u >> 12) - HBASE;
  b = b < 0 ? 0 : (b > (H16BINS - 1) ? (H16BINS - 1) : b);
  return (unsigned int)b;
}

__device__ __forceinline__ unsigned int f2bf(float v) {
  unsigned int u = __float_as_uint(v);
  return (u + 0x7FFFu + ((u >> 16) & 1u)) >> 16;   // RNE
}

__device__ __forceinline__ unsigned long long pack4bf(float4 v) {
  unsigned long long a = (unsigned long long)f2bf(v.x);
  a |= (unsigned long long)f2bf(v.y) << 16;
  a |= (unsigned long long)f2bf(v.z) << 32;
  a |= (unsigned long long)f2bf(v.w) << 48;
  return a;
}

// ---------- precompute: rel table [4096] and wa[4][128] ----------
__global__ void precompute_kernel(const float* __restrict__ query,
                                  const float* __restrict__ rel_w,
                                  const float* __restrict__ rel_b,
                                  const float* __restrict__ W,
                                  const float* __restrict__ a,
                                  float* __restrict__ relflat,
                                  float* __restrict__ wa4) {
  int t = blockIdx.x * blockDim.x + threadIdx.x;
  if (t < 4096) {
    int bq = t >> 11, c = t & 2047;
    const float* q = query + bq * FF;
    const float* w = rel_w + (size_t)c * FF;
    float s = rel_b[c];
#pragma unroll
    for (int f = 0; f < FF; f++) s += q[f] * w[f];
    relflat[t] = s;
  }
  if (t < 512) {
    int i = t >> 7, j = t & 127;
    const float* av = a + i * FF;
    const float* w = W + (size_t)j * FF;
    float s = 0.f;
#pragma unroll
    for (int f = 0; f < FF; f++) s += w[f] * av[f];
    wa4[t] = s;
  }
}

// ---------- CSR builds (once per launch) ----------
__global__ void degcnt_kernel(const int* __restrict__ esrc, const int* __restrict__ edst,
                              unsigned int* __restrict__ deg_s, unsigned int* __restrict__ deg_d) {
  int e = blockIdx.x * blockDim.x + threadIdx.x;
  if (e < EE) {
    atomicAdd(deg_s + esrc[e], 1u);
    atomicAdd(deg_d + edst[e], 1u);
  }
}

__global__ void scan_kernel(const unsigned int* __restrict__ deg,
                            unsigned int* __restrict__ rowptr,
                            unsigned int* __restrict__ rowfill) {
  __shared__ unsigned int sh[1024];
  int t = threadIdx.x;
  const int PER = 20;  // 1024*20 >= NN
  unsigned int loc[PER];
  unsigned int sum = 0;
  int base = t * PER;
#pragma unroll
  for (int i = 0; i < PER; i++) {
    int n = base + i;
    unsigned int d = (n < NN) ? deg[n] : 0u;
    loc[i] = sum;
    sum += d;
  }
  sh[t] = sum;
  __syncthreads();
  for (int o = 1; o < 1024; o <<= 1) {
    unsigned int v = (t >= o) ? sh[t - o] : 0u;
    __syncthreads();
    sh[t] += v;
    __syncthreads();
  }
  unsigned int excl = sh[t] - sum;
#pragma unroll
  for (int i = 0; i < PER; i++) {
    int n = base + i;
    if (n < NN) {
      unsigned int rp = excl + loc[i];
      rowptr[n] = rp;
      rowfill[n] = rp;
    }
  }
  if (t == 1023) rowptr[NN] = EE;
}

// fill both CSRs; src entries packed as e | (r<<19)
__global__ void fill_kernel(const int* __restrict__ esrc, const int* __restrict__ edst,
                            const int* __restrict__ rix,
                            unsigned int* __restrict__ rowfill_s, unsigned int* __restrict__ rowfill_d,
                            unsigned int* __restrict__ cspack_s, int* __restrict__ csre_d) {
  int e = blockIdx.x * blockDim.x + threadIdx.x;
  if (e < EE) {
    unsigned int r = (unsigned int)rix[e];
    unsigned int ss = atomicAdd(rowfill_s + esrc[e], 1u);
    cspack_s[ss] = (unsigned int)e | (r << 19);
    unsigned int sd = atomicAdd(rowfill_d + edst[e], 1u);
    csre_d[sd] = e;
  }
}

// packed_d[p] = src | (r<<20) in dst-CSR order; pos_d[e] = p (inverse perm)
__global__ void gatherd_kernel(const int* __restrict__ csre_d, const int* __restrict__ esrc,
                               const int* __restrict__ rix, unsigned int* __restrict__ packed_d,
                               unsigned int* __restrict__ pos_d) {
  int p = blockIdx.x * blockDim.x + threadIdx.x;
  if (p < EE) {
    int e = csre_d[p];
    packed_d[p] = (unsigned int)esrc[e] | ((unsigned int)rix[e] << 20);
    pos_d[e] = (unsigned int)p;
  }
}

// rewrite cspack_s: replace embedded e with dst-CSR position (both < 2^19)
__global__ void repack_kernel(unsigned int* __restrict__ cspack_s,
                              const unsigned int* __restrict__ pos_d) {
  int i = blockIdx.x * blockDim.x + threadIdx.x;
  if (i < EE) {
    unsigned int cs = cspack_s[i];
    cspack_s[i] = pos_d[cs & 0x7FFFFu] | (cs & 0xFFF80000u);
  }
}

// ---------- init: racc0 and nodewa ----------
__global__ void readout_kernel(const float* __restrict__ x, float* __restrict__ racc) {
  int j = threadIdx.x;  // 0..127
  float acc = 0.f;
  for (int n = blockIdx.x; n < NN; n += gridDim.x) acc += x[(size_t)n * ROW + j];
  atomicAdd(racc + j, acc);
}

__global__ void nodewa_kernel(const float* __restrict__ x, const float* __restrict__ wa,
                              float* __restrict__ nodewa) {
  int wave = threadIdx.x >> 6, lane = threadIdx.x & 63;
  float w0 = wa[lane], w1 = wa[64 + lane];
  for (int n = blockIdx.x * 4 + wave; n < NN; n += gridDim.x * 4) {
    float s = x[(size_t)n * ROW + lane] * w0 + x[(size_t)n * ROW + 64 + lane] * w1;
#pragma unroll
    for (int off = 32; off > 0; off >>= 1) s += __shfl_xor(s, off, 64);
    if (lane == 0) nodewa[n] = s;
  }
}

// ---------- per-src softmax; alpha written in dst-CSR order; 14-bit LDS hist ----------
// state: [0]=bin [1]=krem [2]=T [3]=need [4]=spare [5]=candCnt
__global__ __launch_bounds__(256) void alpha_csr_kernel(
    const unsigned int* __restrict__ rowptr_s, const unsigned int* __restrict__ cspack_s,
    const float* __restrict__ nodewa, const float* __restrict__ relflat,
    const float* __restrict__ wa, float* __restrict__ alpha_d,
    unsigned int* __restrict__ hist16, unsigned int* __restrict__ state) {
  __shared__ float relwa_sh[32];
  __shared__ unsigned int h16[H16BINS];  // 64 KB
  int t = threadIdx.x;
  for (int i = t; i < H16BINS; i += 256) h16[i] = 0u;
  if (t < 32) {
    float s = 0.f;
    const float4* rf = (const float4*)(relflat + t * ROW);
    const float4* wf = (const float4*)wa;
#pragma unroll 8
    for (int j = 0; j < 32; j++) {
      float4 r4 = rf[j], w4 = wf[j];
      s += r4.x * w4.x + r4.y * w4.y + r4.z * w4.z + r4.w * w4.w;
    }
    relwa_sh[t] = s;
  }
  if (blockIdx.x == 0 && t == 255) { state[0] = 0u; state[1] = KTOP; }
  __syncthreads();
  int n = blockIdx.x * 256 + t;
  if (n < NN) {
    unsigned int p0 = rowptr_s[n], p1 = rowptr_s[n + 1];
    float nw = nodewa[n];
    float denom = 0.f;
    for (unsigned int p = p0; p < p1; p++) {
      unsigned int cs = cspack_s[p];
      float v = nw + relwa_sh[cs >> 19];
      v = v > 0.f ? v : NEG_SLOPE * v;
      denom += expf(v);
    }
    float inv = 1.0f / denom;
    for (unsigned int p = p0; p < p1; p++) {
      unsigned int cs = cspack_s[p];
      float v = nw + relwa_sh[cs >> 19];
      v = v > 0.f ? v : NEG_SLOPE * v;
      float av = expf(v) * inv;
      alpha_d[cs & 0x7FFFFu] = av;
      atomicAdd(&h16[bin_of(__float_as_uint(av))], 1u);
    }
  }
  __syncthreads();
  for (int i = t; i < H16BINS; i += 256) {
    unsigned int c = h16[i];
    if (c) atomicAdd(hist16 + i, c);
  }
}

// ---------- select threshold bin; self-zeroes hist16; zeroes racc_next ----------
__global__ void sel16_kernel(unsigned int* __restrict__ state, unsigned int* __restrict__ hist16,
                             float* __restrict__ racc_next) {
  __shared__ unsigned int sh[1024];
  int t = threadIdx.x;
  if (t < 128) racc_next[t] = 0.f;   // consumed later this iter by fused kernel
  unsigned int s = 0;
  const unsigned int* hp = hist16 + t * (H16BINS / 1024);
#pragma unroll
  for (int i = 0; i < H16BINS / 1024; i++) s += hp[i];
  sh[t] = s;
  __syncthreads();
  for (int o = 1; o < 1024; o <<= 1) {
    unsigned int v = (t >= o) ? sh[t - o] : 0u;
    __syncthreads();
    sh[t] += v;
    __syncthreads();
  }
  unsigned int incl = sh[t];
  unsigned int total = sh[1023];
  unsigned int krem = state[1];
  unsigned int cumAbove = total - incl;
  if (t == 0) state[5] = 0u;
  if (cumAbove < krem && cumAbove + s >= krem) {
    unsigned int cum = cumAbove;
    for (int b = H16BINS / 1024 - 1; b >= 0; b--) {
      unsigned int c = hist16[t * (H16BINS / 1024) + b];
      if (cum + c >= krem) {
        state[0] = (unsigned int)(t * (H16BINS / 1024) + b);
        state[1] = krem - cum;
        break;
      }
      cum += c;
    }
  }
  for (int i = 0; i < H16BINS / 1024; i++) hist16[t * (H16BINS / 1024) + i] = 0u;
}

// ---------- collect boundary-bin candidates (block-aggregated append) ----------
__global__ void cand_kernel(const float* __restrict__ alpha_d, unsigned int* __restrict__ state,
                            int* __restrict__ cand_p) {
  __shared__ int lbuf[256];
  __shared__ unsigned int lcnt;
  __shared__ unsigned int gbase;
  int t = threadIdx.x;
  if (t == 0) lcnt = 0u;
  __syncthreads();
  int p = blockIdx.x * 256 + t;
  if (p < EE) {
    unsigned int u = __float_as_uint(alpha_d[p]);
    if (bin_of(u) == state[0]) {
      unsigned int idx = atomicAdd(&lcnt, 1u);
      lbuf[idx] = p;
    }
  }
  __syncthreads();
  if (t == 0 && lcnt) gbase = atomicAdd(state + 5, lcnt);
  __syncthreads();
  if (t < (int)lcnt) {
    unsigned int pos = gbase + t;
    if (pos < CCAP) cand_p[pos] = lbuf[t];
  }
}

// ---------- exact threshold via low-12-bit hist + tiny tie-break (1 block) ----------
__global__ void final_kernel(float* __restrict__ alpha_d, const int* __restrict__ csre_d,
                             const int* __restrict__ cand_p, unsigned int* __restrict__ state) {
  __shared__ unsigned int hlow[4096];   // 16 KB
  __shared__ unsigned int psum[256];
  __shared__ int tiebuf[2048];
  __shared__ unsigned int tcnt;
  __shared__ unsigned int sT, sNeed;
  int t = threadIdx.x;
  unsigned int cnt = state[5];
  if (cnt > CCAP) cnt = CCAP;
  unsigned int krem = state[1];
  for (int i = t; i < 4096; i += 256) hlow[i] = 0u;
  if (t == 0) { tcnt = 0u; sT = 0u; sNeed = 0xFFFFFFFFu; }
  __syncthreads();
  for (unsigned int i = t; i < cnt; i += 256)
    atomicAdd(&hlow[__float_as_uint(alpha_d[cand_p[i]]) & 0xFFFu], 1u);
  __syncthreads();
  unsigned int s = 0;
#pragma unroll
  for (int i = 0; i < 16; i++) s += hlow[t * 16 + i];
  psum[t] = s;
  __syncthreads();
  for (int o = 1; o < 256; o <<= 1) {
    unsigned int v = (t >= o) ? psum[t - o] : 0u;
    __syncthreads();
    psum[t] += v;
    __syncthreads();
  }
  unsigned int total = psum[255];
  unsigned int above_chunk = total - psum[t];
  if (above_chunk < krem && above_chunk + s >= krem) {
    unsigned int cum = above_chunk;
    for (int b = 15; b >= 0; b--) {
      unsigned int c = hlow[t * 16 + b];
      if (cum + c >= krem) {
        sT = ((state[0] + (unsigned int)HBASE) << 12) | (unsigned int)(t * 16 + b);
        sNeed = krem - cum;
        break;
      }
      cum += c;
    }
  }
  __syncthreads();
  unsigned int T = sT, need = sNeed;
  if (t == 0) { state[2] = T; state[3] = need; }
  for (unsigned int i = t; i < cnt; i += 256) {
    int p = cand_p[i];
    if (__float_as_uint(alpha_d[p]) == T) {
      unsigned int idx = atomicAdd(&tcnt, 1u);
      if (idx < 2048) tiebuf[idx] = p;
    }
  }
  __syncthreads();
  unsigned int tc = tcnt;
  if (tc > 2048) tc = 2048;
  if (tc > need) {
    for (unsigned int i = t; i < tc; i += 256) {
      int p = tiebuf[i];
      int e_i = csre_d[p];
      unsigned int rank = 0;
      for (unsigned int j = 0; j < tc; j++) rank += (csre_d[tiebuf[j]] < e_i) ? 1u : 0u;
      if (rank >= need) alpha_d[p] = 0.f;
    }
  }
}

// ---------- FUSED v3: 512 threads / 8 waves; gather (4 nodes/wave) -> barrier ->
// Wsb overlay (reg-preloaded) -> MFMA on waves 0-3. LDS overlay: relf / Wsb share.
__global__ __launch_bounds__(512) void fused_kernel(const unsigned int* __restrict__ rowptr_d,
                                                    const unsigned int* __restrict__ packed_d,
                                                    const float* __restrict__ alpha_d,
                                                    const unsigned int* __restrict__ state,
                                                    const float* __restrict__ x_cur,
                                                    float* __restrict__ x_next,
                                                    const float* __restrict__ relflat,
                                                    const float* __restrict__ layer_w,
                                                    const float* __restrict__ racc_cur,
                                                    const float* __restrict__ tr_w,
                                                    const float* __restrict__ tr_b,
                                                    const float* __restrict__ layer_b,
                                                    const float* __restrict__ ln_g,
                                                    const float* __restrict__ ln_b,
                                                    const float* __restrict__ wa_next,
                                                    float* __restrict__ nodewa,
                                                    float* __restrict__ racc_next) {
  __shared__ __align__(16) char ovl[64 * ASTR * 2];  // 17.4 KB: relf (phase1) / Wsb (phase2)
  __shared__ unsigned short Asb[64 * ASTR];          // 17.4 KB  A=[x|upd] bf16
  __shared__ float trt_sh[128];
  __shared__ float racc_sh[128];
  float* relf = (float*)ovl;                 // [32 * 132]
  unsigned short* Wsb = (unsigned short*)ovl;  // [64 * ASTR]
  int t = threadIdx.x;
  int n0 = blockIdx.x * 32;
  // preload W into registers (in flight during gather)
  float4 wreg[4];
#pragma unroll
  for (int i = 0; i < 4; i++) wreg[i] = ((const float4*)layer_w)[t + i * 512];
  // stage relf (fp32, for gather)
#pragma unroll
  for (int i = 0; i < 2; i++) {
    int q = t + i * 512;                 // float4 idx 0..1023
    int r = q >> 5, kq = q & 31;
    float4 v = ((const float4*)relflat)[q];
    *(float4*)(relf + r * 132 + kq * 4) = v;
  }
  // per-block trt (readout linear + layer_b)
  if (t < 128) {
    int b = t >> 6, f = t & 63;
    const float invN = 1.0f / (float)NN;
    float s = tr_b[f] + layer_b[f];
    const float* rr = racc_cur + b * 64;
    const float* tw = tr_w + f * 64;
#pragma unroll 16
    for (int gg = 0; gg < 64; gg++) s += rr[gg] * invN * tw[gg];
    trt_sh[t] = s;
    racc_sh[t] = 0.f;
  }
  __syncthreads();

  unsigned int T = state[2];
  int lane = t & 63, wv = t >> 6;        // wv in 0..7
  int g = lane >> 4, l = lane & 15;
  // ---- phase 1: gather-reduce 4 nodes per wave (branchless, unroll-2) ----
  for (int i = 0; i < 4; i++) {
    int nl = wv * 4 + i;
    int n = n0 + nl;
    unsigned int p0 = rowptr_d[n], p1 = rowptr_d[n + 1];
    float4 A0 = {0.f, 0.f, 0.f, 0.f}, A1 = {0.f, 0.f, 0.f, 0.f};
    float4 B0 = {0.f, 0.f, 0.f, 0.f}, B1 = {0.f, 0.f, 0.f, 0.f};
    unsigned int base = p0 + g;
    for (; base + 4 < p1; base += 8) {
      float w0 = alpha_d[base];
      unsigned int up0 = packed_d[base];
      float w1 = alpha_d[base + 4];
      unsigned int up1 = packed_d[base + 4];
      w0 = (__float_as_uint(w0) >= T) ? w0 : 0.f;
      w1 = (__float_as_uint(w1) >= T) ? w1 : 0.f;
      const float* xr0 = x_cur + (size_t)(up0 & 0xFFFFFu) * ROW + l * 8;
      const float* rr0 = relf + (up0 >> 20) * 132 + l * 8;
      const float* xr1 = x_cur + (size_t)(up1 & 0xFFFFFu) * ROW + l * 8;
      const float* rr1 = relf + (up1 >> 20) * 132 + l * 8;
      float4 xv00 = *(const float4*)xr0;
      float4 xv01 = *(const float4*)(xr0 + 4);
      float4 xv10 = *(const float4*)xr1;
      float4 xv11 = *(const float4*)(xr1 + 4);
      float4 rv00 = *(const float4*)rr0;
      float4 rv01 = *(const float4*)(rr0 + 4);
      float4 rv10 = *(const float4*)rr1;
      float4 rv11 = *(const float4*)(rr1 + 4);
      A0.x += w0 * (xv00.x + rv00.x); A0.y += w0 * (xv00.y + rv00.y);
      A0.z += w0 * (xv00.z + rv00.z); A0.w += w0 * (xv00.w + rv00.w);
      A1.x += w0 * (xv01.x + rv01.x); A1.y += w0 * (xv01.y + rv01.y);
      A1.z += w0 * (xv01.z + rv01.z); A1.w += w0 * (xv01.w + rv01.w);
      B0.x += w1 * (xv10.x + rv10.x); B0.y += w1 * (xv10.y + rv10.y);
      B0.z += w1 * (xv10.z + rv10.z); B0.w += w1 * (xv10.w + rv10.w);
      B1.x += w1 * (xv11.x + rv11.x); B1.y += w1 * (xv11.y + rv11.y);
      B1.z += w1 * (xv11.z + rv11.z); B1.w += w1 * (xv11.w + rv11.w);
    }
    if (base < p1) {
      float w0 = alpha_d[base];
      unsigned int up0 = packed_d[base];
      w0 = (__float_as_uint(w0) >= T) ? w0 : 0.f;
      const float* xr0 = x_cur + (size_t)(up0 & 0xFFFFFu) * ROW + l * 8;
      const float* rr0 = relf + (up0 >> 20) * 132 + l * 8;
      float4 xv00 = *(const float4*)xr0;
      float4 xv01 = *(const float4*)(xr0 + 4);
      float4 rv00 = *(const float4*)rr0;
      float4 rv01 = *(const float4*)(rr0 + 4);
      A0.x += w0 * (xv00.x + rv00.x); A0.y += w0 * (xv00.y + rv00.y);
      A0.z += w0 * (xv00.z + rv00.z); A0.w += w0 * (xv00.w + rv00.w);
      A1.x += w0 * (xv01.x + rv01.x); A1.y += w0 * (xv01.y + rv01.y);
      A1.z += w0 * (xv01.z + rv01.z); A1.w += w0 * (xv01.w + rv01.w);
    }
    A0.x += B0.x; A0.y += B0.y; A0.z += B0.z; A0.w += B0.w;
    A1.x += B1.x; A1.y += B1.y; A1.z += B1.z; A1.w += B1.w;
#pragma unroll
    for (int off = 16; off <= 32; off <<= 1) {
      A0.x += __shfl_xor(A0.x, off, 64); A0.y += __shfl_xor(A0.y, off, 64);
      A0.z += __shfl_xor(A0.z, off, 64); A0.w += __shfl_xor(A0.w, off, 64);
      A1.x += __shfl_xor(A1.x, off, 64); A1.y += __shfl_xor(A1.y, off, 64);
      A1.z += __shfl_xor(A1.z, off, 64); A1.w += __shfl_xor(A1.w, off, 64);
    }
    if (g == 0) {
      // lane l holds floats l*8..l*8+7 of the 128-float row
      const float* xn = x_cur + (size_t)n * ROW + l * 8;
      float4 xs0 = *(const float4*)xn;
      float4 xs1 = *(const float4*)(xn + 4);
      float4 u0 = {A0.x + xs0.x, A0.y + xs0.y, A0.z + xs0.z, A0.w + xs0.w};
      float4 u1 = {A1.x + xs1.x, A1.y + xs1.y, A1.z + xs1.z, A1.w + xs1.w};
      int m = nl * 2 + (l >> 3);          // A-tile row
      int f8 = (l & 7) * 8;               // col offset within 64
      unsigned short* arow = Asb + m * ASTR;
      *(unsigned long long*)(arow + f8) = pack4bf(xs0);
      *(unsigned long long*)(arow + f8 + 4) = pack4bf(xs1);
      *(unsigned long long*)(arow + 64 + f8) = pack4bf(u0);
      *(unsigned long long*)(arow + 64 + f8 + 4) = pack4bf(u1);
    }
  }
  __syncthreads();   // relf reads done; Asb complete
  // write Wsb from registers (overlay region, natural [f][c] = MFMA B-frag layout)
#pragma unroll
  for (int i = 0; i < 4; i++) {
    int Q = t + i * 512;
    int f = Q >> 5, c4 = Q & 31;
    *(unsigned long long*)(Wsb + f * ASTR + c4 * 4) = pack4bf(wreg[i]);
  }
  __syncthreads();
  // ---- phase 2: MFMA + epilogue on waves 0..3 ----
  if (wv < 4) {
    int mt = wv;
    int l15 = l, q = g;
    const unsigned short* arow = Asb + (mt * 16 + l15) * ASTR + q * 8;
    f32x4 acc[4] = {{0.f, 0.f, 0.f, 0.f}, {0.f, 0.f, 0.f, 0.f},
                    {0.f, 0.f, 0.f, 0.f}, {0.f, 0.f, 0.f, 0.f}};
#pragma unroll
    for (int ks = 0; ks < 4; ks++) {
      short8 a = *(const short8*)(arow + ks * 32);
#pragma unroll
      for (int nt = 0; nt < 4; nt++) {
        short8 b = *(const short8*)(Wsb + (nt * 16 + l15) * ASTR + ks * 32 + q * 8);
        acc[nt] = __builtin_amdgcn_mfma_f32_16x16x32_bf16(a, b, acc[nt], 0, 0, 0);
      }
    }
    float g_[4], bta[4], wn0[4], wn1[4], tr0[4], tr1[4];
#pragma unroll
    for (int nt = 0; nt < 4; nt++) {
      int f = nt * 16 + l15;
      g_[nt] = ln_g[f]; bta[nt] = ln_b[f];
      wn0[nt] = wa_next[f]; wn1[nt] = wa_next[64 + f];
      tr0[nt] = trt_sh[f]; tr1[nt] = trt_sh[64 + f];
    }
    const float invF = 1.0f / (float)FF;
    float y[4][4];
#pragma unroll
    for (int r = 0; r < 4; r++) {
      int b = r & 1;
      float o[4];
      float s = 0.f, qq = 0.f;
#pragma unroll
      for (int nt = 0; nt < 4; nt++) {
        float v = acc[nt][r] + (b ? tr1[nt] : tr0[nt]);
        o[nt] = v; s += v; qq += v * v;
      }
#pragma unroll
      for (int off = 1; off < 16; off <<= 1) {
        s += __shfl_xor(s, off, 64);
        qq += __shfl_xor(qq, off, 64);
      }
      float mu = s * invF;
      float var = qq * invF - mu * mu;
      float rstd = 1.0f / sqrtf(var + LN_EPS);
      int nl = mt * 8 + q * 2 + (r >> 1);
      size_t base = (size_t)(n0 + nl) * ROW + b * 64 + l15;
#pragma unroll
      for (int nt = 0; nt < 4; nt++) {
        float xo = x_cur[base + nt * 16];
        float on = (o[nt] - mu) * rstd * g_[nt] + bta[nt];
        float h = on > 0.f ? on : expm1f(on);
        float yy = h + xo;
        y[r][nt] = yy;
        x_next[base + nt * 16] = yy;
      }
    }
#pragma unroll
    for (int b = 0; b < 2; b++) {
#pragma unroll
      for (int nt = 0; nt < 4; nt++) {
        atomicAdd(&racc_sh[b * 64 + nt * 16 + l15], y[b][nt] + y[b + 2][nt]);
      }
    }
#pragma unroll
    for (int rp = 0; rp < 2; rp++) {
      float nw = 0.f;
#pragma unroll
      for (int nt = 0; nt < 4; nt++)
        nw += y[2 * rp][nt] * wn0[nt] + y[2 * rp + 1][nt] * wn1[nt];
#pragma unroll
      for (int off = 1; off < 16; off <<= 1) nw += __shfl_xor(nw, off, 64);
      if (l15 == 0) nodewa[n0 + mt * 8 + q * 2 + rp] = nw;
    }
  }
  __syncthreads();
  if (t < 128) atomicAdd(racc_next + t, racc_sh[t]);
}

extern "C" void kernel_launch(void* const* d_in, const int* in_sizes, int n_in,
                              void* d_out, int out_size, void* d_ws, size_t ws_size,
                              hipStream_t stream) {
  const int* ei = (const int*)d_in[0];
  const int* esrc = ei;
  const int* edst = ei + EE;
  const int* rix = (const int*)d_in[1];
  const float* boundary = (const float*)d_in[2];
  const float* query = (const float*)d_in[3];
  const float* rel_w = (const float*)d_in[4];
  const float* rel_b = (const float*)d_in[5];
  const float* layer_w = (const float*)d_in[6];
  const float* layer_b = (const float*)d_in[7];
  const float* tr_w = (const float*)d_in[8];
  const float* tr_b = (const float*)d_in[9];
  const float* Wm = (const float*)d_in[10];
  const float* av = (const float*)d_in[11];
  const float* ln_g = (const float*)d_in[12];
  const float* ln_b = (const float*)d_in[13];
  float* x = (float*)d_out;

  char* ws = (char*)d_ws;
  size_t off = 0;
  auto allocf = [&](size_t n) -> float* {
    float* p = (float*)(ws + off);
    off += ((n * 4 + 255) / 256) * 256;
    return p;
  };
  auto allocu = [&](size_t n) -> unsigned int* {
    unsigned int* p = (unsigned int*)(ws + off);
    off += ((n * 4 + 255) / 256) * 256;
    return p;
  };
  float* relflat = allocf(4096);
  float* wa4 = allocf(512);
  float* alpha_d = allocf(EE);       // alpha in dst-CSR order
  float* xbuf = allocf((size_t)NN * ROW);   // ping-pong partner of d_out
  float* racc0 = allocf(128);
  float* racc1 = allocf(128);
  float* nodewa = allocf(NN);
  unsigned int* hist16 = allocu(H16BINS);
  unsigned int* state = allocu(8);
  unsigned int* deg_s = allocu(NN);
  unsigned int* deg_d = allocu(NN);
  unsigned int* rowptr_s = allocu(NN + 1);
  unsigned int* rowptr_d = allocu(NN + 1);
  unsigned int* rowfill_s = allocu(NN);
  unsigned int* rowfill_d = allocu(NN);
  unsigned int* cspack_s = allocu(EE);
  int* csre_d = (int*)allocu(EE);
  unsigned int* packed_d = allocu(EE);
  unsigned int* pos_d = allocu(EE);
  int* cand_p = (int*)allocu(CCAP);
  float* rbuf[2] = {racc0, racc1};

  hipMemcpyAsync(x, boundary, (size_t)NN * ROW * 4, hipMemcpyDeviceToDevice, stream);
  hipMemsetAsync(deg_s, 0, NN * 4, stream);
  hipMemsetAsync(deg_d, 0, NN * 4, stream);
  hipMemsetAsync(racc0, 0, 128 * 4, stream);
  hipMemsetAsync(hist16, 0, H16BINS * 4, stream);   // once; sel16 self-zeroes per iter
  precompute_kernel<<<16, 256, 0, stream>>>(query, rel_w, rel_b, Wm, av, relflat, wa4);

  // CSR builds (edge_index constant for this launch)
  degcnt_kernel<<<EE / 256, 256, 0, stream>>>(esrc, edst, deg_s, deg_d);
  scan_kernel<<<1, 1024, 0, stream>>>(deg_s, rowptr_s, rowfill_s);
  scan_kernel<<<1, 1024, 0, stream>>>(deg_d, rowptr_d, rowfill_d);
  fill_kernel<<<EE / 256, 256, 0, stream>>>(esrc, edst, rix, rowfill_s, rowfill_d, cspack_s, csre_d);
  gatherd_kernel<<<EE / 256, 256, 0, stream>>>(csre_d, esrc, rix, packed_d, pos_d);
  repack_kernel<<<EE / 256, 256, 0, stream>>>(cspack_s, pos_d);

  // iter-0 readout sum and nodewa (from x = d_out)
  readout_kernel<<<256, 128, 0, stream>>>(x, racc0);
  nodewa_kernel<<<1250, 256, 0, stream>>>(x, wa4, nodewa);

  for (int it = 0; it < 4; it++) {
    float* rcur = rbuf[it & 1];
    float* rnxt = rbuf[(it + 1) & 1];
    const float* wa_it = wa4 + it * 128;
    const float* wa_nx = wa4 + (it < 3 ? it + 1 : 3) * 128;
    float* x_cur = (it & 1) ? xbuf : x;
    float* x_nxt = (it & 1) ? x : xbuf;

    alpha_csr_kernel<<<(NN + 255) / 256, 256, 0, stream>>>(rowptr_s, cspack_s, nodewa,
                                                           relflat, wa_it, alpha_d, hist16, state);
    sel16_kernel<<<1, 1024, 0, stream>>>(state, hist16, rnxt);
    cand_kernel<<<EE / 256, 256, 0, stream>>>(alpha_d, state, cand_p);
    final_kernel<<<1, 256, 0, stream>>>(alpha_d, csre_d, cand_p, state);

    fused_kernel<<<625, 512, 0, stream>>>(rowptr_d, packed_d, alpha_d, state,
                                          x_cur, x_nxt, relflat, layer_w,
                                          rcur, tr_w, tr_b, layer_b, ln_g, ln_b,
                                          wa_nx, nodewa, rnxt);
  }
}

// Round 14
// 642.735 us; speedup vs baseline: 1.0869x; 1.0869x over previous
//
#include <hip/hip_runtime.h>
#include <stdint.h>

#define NN 20000
#define EE 320000
#define FF 64
#define ROW 128              // B*F
#define KTOP 160000
#define NEG_SLOPE 0.2f
#define LN_EPS 1e-5f
#define H16BINS 16384        // (u>>12) - (120<<11), clamped: covers alpha in [2^-7, 1]
#define HBASE (120 << 11)
#define CCAP 16384
#define ASTR 136             // bf16 stride for MFMA LDS tiles (16B-aligned frag reads)

typedef __attribute__((ext_vector_type(8))) short short8;
typedef __attribute__((ext_vector_type(4))) float f32x4;

__device__ __forceinline__ unsigned int bin_of(unsigned int u) {
  int b = (int)(u >> 12) - HBASE;
  b = b < 0 ? 0 : (b > (H16BINS - 1) ? (H16BINS - 1) : b);
  return (unsigned int)b;
}

__device__ __forceinline__ unsigned int f2bf(float v) {
  unsigned int u = __float_as_uint(v);
  return (u + 0x7FFFu + ((u >> 16) & 1u)) >> 16;   // RNE
}

__device__ __forceinline__ unsigned long long pack4bf(float4 v) {
  unsigned long long a = (unsigned long long)f2bf(v.x);
  a |= (unsigned long long)f2bf(v.y) << 16;
  a |= (unsigned long long)f2bf(v.z) << 32;
  a |= (unsigned long long)f2bf(v.w) << 48;
  return a;
}

// ---------- precompute: rel table [4096] and wa[4][128] ----------
__global__ void precompute_kernel(const float* __restrict__ query,
                                  const float* __restrict__ rel_w,
                                  const float* __restrict__ rel_b,
                                  const float* __restrict__ W,
                                  const float* __restrict__ a,
                                  float* __restrict__ relflat,
                                  float* __restrict__ wa4) {
  int t = blockIdx.x * blockDim.x + threadIdx.x;
  if (t < 4096) {
    int bq = t >> 11, c = t & 2047;
    const float* q = query + bq * FF;
    const float* w = rel_w + (size_t)c * FF;
    float s = rel_b[c];
#pragma unroll
    for (int f = 0; f < FF; f++) s += q[f] * w[f];
    relflat[t] = s;
  }
  if (t < 512) {
    int i = t >> 7, j = t & 127;
    const float* av = a + i * FF;
    const float* w = W + (size_t)j * FF;
    float s = 0.f;
#pragma unroll
    for (int f = 0; f < FF; f++) s += w[f] * av[f];
    wa4[t] = s;
  }
}

// ---------- CSR builds (once per launch) ----------
__global__ void degcnt_kernel(const int* __restrict__ esrc, const int* __restrict__ edst,
                              unsigned int* __restrict__ deg_s, unsigned int* __restrict__ deg_d) {
  int e = blockIdx.x * blockDim.x + threadIdx.x;
  if (e < EE) {
    atomicAdd(deg_s + esrc[e], 1u);
    atomicAdd(deg_d + edst[e], 1u);
  }
}

__global__ void scan_kernel(const unsigned int* __restrict__ deg,
                            unsigned int* __restrict__ rowptr,
                            unsigned int* __restrict__ rowfill) {
  __shared__ unsigned int sh[1024];
  int t = threadIdx.x;
  const int PER = 20;  // 1024*20 >= NN
  unsigned int loc[PER];
  unsigned int sum = 0;
  int base = t * PER;
#pragma unroll
  for (int i = 0; i < PER; i++) {
    int n = base + i;
    unsigned int d = (n < NN) ? deg[n] : 0u;
    loc[i] = sum;
    sum += d;
  }
  sh[t] = sum;
  __syncthreads();
  for (int o = 1; o < 1024; o <<= 1) {
    unsigned int v = (t >= o) ? sh[t - o] : 0u;
    __syncthreads();
    sh[t] += v;
    __syncthreads();
  }
  unsigned int excl = sh[t] - sum;
#pragma unroll
  for (int i = 0; i < PER; i++) {
    int n = base + i;
    if (n < NN) {
      unsigned int rp = excl + loc[i];
      rowptr[n] = rp;
      rowfill[n] = rp;
    }
  }
  if (t == 1023) rowptr[NN] = EE;
}

// fill both CSRs; src entries packed as e | (r<<19)
__global__ void fill_kernel(const int* __restrict__ esrc, const int* __restrict__ edst,
                            const int* __restrict__ rix,
                            unsigned int* __restrict__ rowfill_s, unsigned int* __restrict__ rowfill_d,
                            unsigned int* __restrict__ cspack_s, int* __restrict__ csre_d) {
  int e = blockIdx.x * blockDim.x + threadIdx.x;
  if (e < EE) {
    unsigned int r = (unsigned int)rix[e];
    unsigned int ss = atomicAdd(rowfill_s + esrc[e], 1u);
    cspack_s[ss] = (unsigned int)e | (r << 19);
    unsigned int sd = atomicAdd(rowfill_d + edst[e], 1u);
    csre_d[sd] = e;
  }
}

// packed_d[p] = src | (r<<20) in dst-CSR order; pos_d[e] = p (inverse perm)
__global__ void gatherd_kernel(const int* __restrict__ csre_d, const int* __restrict__ esrc,
                               const int* __restrict__ rix, unsigned int* __restrict__ packed_d,
                               unsigned int* __restrict__ pos_d) {
  int p = blockIdx.x * blockDim.x + threadIdx.x;
  if (p < EE) {
    int e = csre_d[p];
    packed_d[p] = (unsigned int)esrc[e] | ((unsigned int)rix[e] << 20);
    pos_d[e] = (unsigned int)p;
  }
}

// rewrite cspack_s: replace embedded e with dst-CSR position (both < 2^19)
__global__ void repack_kernel(unsigned int* __restrict__ cspack_s,
                              const unsigned int* __restrict__ pos_d) {
  int i = blockIdx.x * blockDim.x + threadIdx.x;
  if (i < EE) {
    unsigned int cs = cspack_s[i];
    cspack_s[i] = pos_d[cs & 0x7FFFFu] | (cs & 0xFFF80000u);
  }
}

// ---------- init: racc0 and nodewa ----------
__global__ void readout_kernel(const float* __restrict__ x, float* __restrict__ racc) {
  int j = threadIdx.x;  // 0..127
  float acc = 0.f;
  for (int n = blockIdx.x; n < NN; n += gridDim.x) acc += x[(size_t)n * ROW + j];
  atomicAdd(racc + j, acc);
}

__global__ void nodewa_kernel(const float* __restrict__ x, const float* __restrict__ wa,
                              float* __restrict__ nodewa) {
  int wave = threadIdx.x >> 6, lane = threadIdx.x & 63;
  float w0 = wa[lane], w1 = wa[64 + lane];
  for (int n = blockIdx.x * 4 + wave; n < NN; n += gridDim.x * 4) {
    float s = x[(size_t)n * ROW + lane] * w0 + x[(size_t)n * ROW + 64 + lane] * w1;
#pragma unroll
    for (int off = 32; off > 0; off >>= 1) s += __shfl_xor(s, off, 64);
    if (lane == 0) nodewa[n] = s;
  }
}

// ---------- per-src softmax v2: 4 lanes per node (64 nodes/block, 313 blocks) ----------
// state: [0]=bin [1]=krem [2]=T [3]=need [4]=spare [5]=candCnt
__global__ __launch_bounds__(256) void alpha_csr_kernel(
    const unsigned int* __restrict__ rowptr_s, const unsigned int* __restrict__ cspack_s,
    const float* __restrict__ nodewa, const float* __restrict__ relflat,
    const float* __restrict__ wa, float* __restrict__ alpha_d,
    unsigned int* __restrict__ hist16, unsigned int* __restrict__ state) {
  __shared__ float relwa_sh[32];
  __shared__ unsigned int h16[H16BINS];  // 64 KB
  int t = threadIdx.x;
  for (int i = t; i < H16BINS; i += 256) h16[i] = 0u;
  if (t < 32) {
    float s = 0.f;
    const float4* rf = (const float4*)(relflat + t * ROW);
    const float4* wf = (const float4*)wa;
#pragma unroll 8
    for (int j = 0; j < 32; j++) {
      float4 r4 = rf[j], w4 = wf[j];
      s += r4.x * w4.x + r4.y * w4.y + r4.z * w4.z + r4.w * w4.w;
    }
    relwa_sh[t] = s;
  }
  if (blockIdx.x == 0 && t == 255) { state[0] = 0u; state[1] = KTOP; }
  __syncthreads();
  int n = blockIdx.x * 64 + (t >> 2);   // 4 lanes per node
  int sl = t & 3;
  if (n < NN) {
    unsigned int p0 = rowptr_s[n], p1 = rowptr_s[n + 1];
    float nw = nodewa[n];
    float dpart = 0.f;
    for (unsigned int p = p0 + sl; p < p1; p += 4) {
      unsigned int cs = cspack_s[p];
      float v = nw + relwa_sh[cs >> 19];
      v = v > 0.f ? v : NEG_SLOPE * v;
      dpart += expf(v);
    }
    // combine partial denoms across the node's 4 contiguous lanes
    dpart += __shfl_xor(dpart, 1, 64);
    dpart += __shfl_xor(dpart, 2, 64);
    float inv = 1.0f / dpart;
    for (unsigned int p = p0 + sl; p < p1; p += 4) {
      unsigned int cs = cspack_s[p];
      float v = nw + relwa_sh[cs >> 19];
      v = v > 0.f ? v : NEG_SLOPE * v;
      float av = expf(v) * inv;
      alpha_d[cs & 0x7FFFFu] = av;
      atomicAdd(&h16[bin_of(__float_as_uint(av))], 1u);
    }
  }
  __syncthreads();
  for (int i = t; i < H16BINS; i += 256) {
    unsigned int c = h16[i];
    if (c) atomicAdd(hist16 + i, c);
  }
}

// ---------- select threshold bin; self-zeroes hist16; zeroes racc_next ----------
__global__ void sel16_kernel(unsigned int* __restrict__ state, unsigned int* __restrict__ hist16,
                             float* __restrict__ racc_next) {
  __shared__ unsigned int sh[1024];
  int t = threadIdx.x;
  if (t < 128) racc_next[t] = 0.f;   // consumed later this iter by fused kernel
  unsigned int s = 0;
  const unsigned int* hp = hist16 + t * (H16BINS / 1024);
#pragma unroll
  for (int i = 0; i < H16BINS / 1024; i++) s += hp[i];
  sh[t] = s;
  __syncthreads();
  for (int o = 1; o < 1024; o <<= 1) {
    unsigned int v = (t >= o) ? sh[t - o] : 0u;
    __syncthreads();
    sh[t] += v;
    __syncthreads();
  }
  unsigned int incl = sh[t];
  unsigned int total = sh[1023];
  unsigned int krem = state[1];
  unsigned int cumAbove = total - incl;
  if (t == 0) state[5] = 0u;
  if (cumAbove < krem && cumAbove + s >= krem) {
    unsigned int cum = cumAbove;
    for (int b = H16BINS / 1024 - 1; b >= 0; b--) {
      unsigned int c = hist16[t * (H16BINS / 1024) + b];
      if (cum + c >= krem) {
        state[0] = (unsigned int)(t * (H16BINS / 1024) + b);
        state[1] = krem - cum;
        break;
      }
      cum += c;
    }
  }
  for (int i = 0; i < H16BINS / 1024; i++) hist16[t * (H16BINS / 1024) + i] = 0u;
}

// ---------- collect boundary-bin candidates (block-aggregated append) ----------
__global__ void cand_kernel(const float* __restrict__ alpha_d, unsigned int* __restrict__ state,
                            int* __restrict__ cand_p) {
  __shared__ int lbuf[256];
  __shared__ unsigned int lcnt;
  __shared__ unsigned int gbase;
  int t = threadIdx.x;
  if (t == 0) lcnt = 0u;
  __syncthreads();
  int p = blockIdx.x * 256 + t;
  if (p < EE) {
    unsigned int u = __float_as_uint(alpha_d[p]);
    if (bin_of(u) == state[0]) {
      unsigned int idx = atomicAdd(&lcnt, 1u);
      lbuf[idx] = p;
    }
  }
  __syncthreads();
  if (t == 0 && lcnt) gbase = atomicAdd(state + 5, lcnt);
  __syncthreads();
  if (t < (int)lcnt) {
    unsigned int pos = gbase + t;
    if (pos < CCAP) cand_p[pos] = lbuf[t];
  }
}

// ---------- exact threshold via low-12-bit hist + tiny tie-break (1 block) ----------
__global__ void final_kernel(float* __restrict__ alpha_d, const int* __restrict__ csre_d,
                             const int* __restrict__ cand_p, unsigned int* __restrict__ state) {
  __shared__ unsigned int hlow[4096];   // 16 KB
  __shared__ unsigned int psum[256];
  __shared__ int tiebuf[2048];
  __shared__ unsigned int tcnt;
  __shared__ unsigned int sT, sNeed;
  int t = threadIdx.x;
  unsigned int cnt = state[5];
  if (cnt > CCAP) cnt = CCAP;
  unsigned int krem = state[1];
  for (int i = t; i < 4096; i += 256) hlow[i] = 0u;
  if (t == 0) { tcnt = 0u; sT = 0u; sNeed = 0xFFFFFFFFu; }
  __syncthreads();
  for (unsigned int i = t; i < cnt; i += 256)
    atomicAdd(&hlow[__float_as_uint(alpha_d[cand_p[i]]) & 0xFFFu], 1u);
  __syncthreads();
  unsigned int s = 0;
#pragma unroll
  for (int i = 0; i < 16; i++) s += hlow[t * 16 + i];
  psum[t] = s;
  __syncthreads();
  for (int o = 1; o < 256; o <<= 1) {
    unsigned int v = (t >= o) ? psum[t - o] : 0u;
    __syncthreads();
    psum[t] += v;
    __syncthreads();
  }
  unsigned int total = psum[255];
  unsigned int above_chunk = total - psum[t];
  if (above_chunk < krem && above_chunk + s >= krem) {
    unsigned int cum = above_chunk;
    for (int b = 15; b >= 0; b--) {
      unsigned int c = hlow[t * 16 + b];
      if (cum + c >= krem) {
        sT = ((state[0] + (unsigned int)HBASE) << 12) | (unsigned int)(t * 16 + b);
        sNeed = krem - cum;
        break;
      }
      cum += c;
    }
  }
  __syncthreads();
  unsigned int T = sT, need = sNeed;
  if (t == 0) { state[2] = T; state[3] = need; }
  for (unsigned int i = t; i < cnt; i += 256) {
    int p = cand_p[i];
    if (__float_as_uint(alpha_d[p]) == T) {
      unsigned int idx = atomicAdd(&tcnt, 1u);
      if (idx < 2048) tiebuf[idx] = p;
    }
  }
  __syncthreads();
  unsigned int tc = tcnt;
  if (tc > 2048) tc = 2048;
  if (tc > need) {
    for (unsigned int i = t; i < tc; i += 256) {
      int p = tiebuf[i];
      int e_i = csre_d[p];
      unsigned int rank = 0;
      for (unsigned int j = 0; j < tc; j++) rank += (csre_d[tiebuf[j]] < e_i) ? 1u : 0u;
      if (rank >= need) alpha_d[p] = 0.f;
    }
  }
}

// ---------- FUSED (R12): edge gather-reduce + bf16 MFMA GEMM + LN + ELU + residual ----------
// Ping-pong: reads x_cur (never written this iter), writes x_next.
// Block = 32 nodes = 64 M-rows. Wave w: phase 1 gathers nodes w*8..w*8+7 and writes
// A-tile rows 16w..16w+15 (its own), phase 2 MFMAs those same rows — no inter-phase barrier.
// Gather is branchless (mask via select, loads always issue) + unroll-2 for MLP.
__global__ __launch_bounds__(256) void fused_kernel(const unsigned int* __restrict__ rowptr_d,
                                                    const unsigned int* __restrict__ packed_d,
                                                    const float* __restrict__ alpha_d,
                                                    const unsigned int* __restrict__ state,
                                                    const float* __restrict__ x_cur,
                                                    float* __restrict__ x_next,
                                                    const float* __restrict__ relflat,
                                                    const float* __restrict__ layer_w,
                                                    const float* __restrict__ racc_cur,
                                                    const float* __restrict__ tr_w,
                                                    const float* __restrict__ tr_b,
                                                    const float* __restrict__ layer_b,
                                                    const float* __restrict__ ln_g,
                                                    const float* __restrict__ ln_b,
                                                    const float* __restrict__ wa_next,
                                                    float* __restrict__ nodewa,
                                                    float* __restrict__ racc_next) {
  __shared__ float relf[32 * 132];           // 16.9 KB
  __shared__ unsigned short Asb[64 * ASTR];  // 17.4 KB  A=[x|upd] bf16
  __shared__ unsigned short Wsb[64 * ASTR];  // 17.4 KB  layer_w natural [f][c] bf16
  __shared__ float trt_sh[128];
  __shared__ float racc_sh[128];
  int t = threadIdx.x;
  int n0 = blockIdx.x * 32;
  // stage relf (fp32, for gather) and Wsb (bf16, for GEMM)
#pragma unroll
  for (int i = 0; i < 4; i++) {
    int q = t + i * 256;                 // float4 idx 0..1023
    int r = q >> 5, kq = q & 31;
    float4 v = ((const float4*)relflat)[q];
    *(float4*)(relf + r * 132 + kq * 4) = v;
  }
#pragma unroll
  for (int i = 0; i < 8; i++) {
    int Q = t + i * 256;                  // 0..2047 float4s
    int f = Q >> 5, c4 = Q & 31;
    float4 wv = ((const float4*)layer_w)[Q];
    *(unsigned long long*)(Wsb + f * ASTR + c4 * 4) = pack4bf(wv);
  }
  // per-block trt (readout linear + layer_b)
  if (t < 128) {
    int b = t >> 6, f = t & 63;
    const float invN = 1.0f / (float)NN;
    float s = tr_b[f] + layer_b[f];
    const float* rr = racc_cur + b * 64;
    const float* tw = tr_w + f * 64;
#pragma unroll 16
    for (int gg = 0; gg < 64; gg++) s += rr[gg] * invN * tw[gg];
    trt_sh[t] = s;
    racc_sh[t] = 0.f;
  }
  __syncthreads();

  unsigned int T = state[2];
  int lane = t & 63, mt = t >> 6;
  int g = lane >> 4, l = lane & 15;
  // ---- phase 1: gather-reduce 8 nodes for this wave (branchless, unroll-2) ----
  for (int i = 0; i < 8; i++) {
    int nl = mt * 8 + i;
    int n = n0 + nl;
    unsigned int p0 = rowptr_d[n], p1 = rowptr_d[n + 1];
    float4 A0 = {0.f, 0.f, 0.f, 0.f}, A1 = {0.f, 0.f, 0.f, 0.f};
    float4 B0 = {0.f, 0.f, 0.f, 0.f}, B1 = {0.f, 0.f, 0.f, 0.f};
    unsigned int base = p0 + g;
    for (; base + 4 < p1; base += 8) {
      float w0 = alpha_d[base];
      unsigned int up0 = packed_d[base];
      float w1 = alpha_d[base + 4];
      unsigned int up1 = packed_d[base + 4];
      w0 = (__float_as_uint(w0) >= T) ? w0 : 0.f;
      w1 = (__float_as_uint(w1) >= T) ? w1 : 0.f;
      const float* xr0 = x_cur + (size_t)(up0 & 0xFFFFFu) * ROW + l * 8;
      const float* rr0 = relf + (up0 >> 20) * 132 + l * 8;
      const float* xr1 = x_cur + (size_t)(up1 & 0xFFFFFu) * ROW + l * 8;
      const float* rr1 = relf + (up1 >> 20) * 132 + l * 8;
      float4 xv00 = *(const float4*)xr0;
      float4 xv01 = *(const float4*)(xr0 + 4);
      float4 xv10 = *(const float4*)xr1;
      float4 xv11 = *(const float4*)(xr1 + 4);
      float4 rv00 = *(const float4*)rr0;
      float4 rv01 = *(const float4*)(rr0 + 4);
      float4 rv10 = *(const float4*)rr1;
      float4 rv11 = *(const float4*)(rr1 + 4);
      A0.x += w0 * (xv00.x + rv00.x); A0.y += w0 * (xv00.y + rv00.y);
      A0.z += w0 * (xv00.z + rv00.z); A0.w += w0 * (xv00.w + rv00.w);
      A1.x += w0 * (xv01.x + rv01.x); A1.y += w0 * (xv01.y + rv01.y);
      A1.z += w0 * (xv01.z + rv01.z); A1.w += w0 * (xv01.w + rv01.w);
      B0.x += w1 * (xv10.x + rv10.x); B0.y += w1 * (xv10.y + rv10.y);
      B0.z += w1 * (xv10.z + rv10.z); B0.w += w1 * (xv10.w + rv10.w);
      B1.x += w1 * (xv11.x + rv11.x); B1.y += w1 * (xv11.y + rv11.y);
      B1.z += w1 * (xv11.z + rv11.z); B1.w += w1 * (xv11.w + rv11.w);
    }
    if (base < p1) {
      float w0 = alpha_d[base];
      unsigned int up0 = packed_d[base];
      w0 = (__float_as_uint(w0) >= T) ? w0 : 0.f;
      const float* xr0 = x_cur + (size_t)(up0 & 0xFFFFFu) * ROW + l * 8;
      const float* rr0 = relf + (up0 >> 20) * 132 + l * 8;
      float4 xv00 = *(const float4*)xr0;
      float4 xv01 = *(const float4*)(xr0 + 4);
      float4 rv00 = *(const float4*)rr0;
      float4 rv01 = *(const float4*)(rr0 + 4);
      A0.x += w0 * (xv00.x + rv00.x); A0.y += w0 * (xv00.y + rv00.y);
      A0.z += w0 * (xv00.z + rv00.z); A0.w += w0 * (xv00.w + rv00.w);
      A1.x += w0 * (xv01.x + rv01.x); A1.y += w0 * (xv01.y + rv01.y);
      A1.z += w0 * (xv01.z + rv01.z); A1.w += w0 * (xv01.w + rv01.w);
    }
    A0.x += B0.x; A0.y += B0.y; A0.z += B0.z; A0.w += B0.w;
    A1.x += B1.x; A1.y += B1.y; A1.z += B1.z; A1.w += B1.w;
#pragma unroll
    for (int off = 16; off <= 32; off <<= 1) {
      A0.x += __shfl_xor(A0.x, off, 64); A0.y += __shfl_xor(A0.y, off, 64);
      A0.z += __shfl_xor(A0.z, off, 64); A0.w += __shfl_xor(A0.w, off, 64);
      A1.x += __shfl_xor(A1.x, off, 64); A1.y += __shfl_xor(A1.y, off, 64);
      A1.z += __shfl_xor(A1.z, off, 64); A1.w += __shfl_xor(A1.w, off, 64);
    }
    if (g == 0) {
      // lane l holds floats l*8..l*8+7 of the 128-float row: b = l>=8
      const float* xn = x_cur + (size_t)n * ROW + l * 8;
      float4 xs0 = *(const float4*)xn;
      float4 xs1 = *(const float4*)(xn + 4);
      float4 u0 = {A0.x + xs0.x, A0.y + xs0.y, A0.z + xs0.z, A0.w + xs0.w};
      float4 u1 = {A1.x + xs1.x, A1.y + xs1.y, A1.z + xs1.z, A1.w + xs1.w};
      int m = nl * 2 + (l >> 3);          // A-tile row
      int f8 = (l & 7) * 8;               // col offset within 64
      unsigned short* arow = Asb + m * ASTR;
      *(unsigned long long*)(arow + f8) = pack4bf(xs0);
      *(unsigned long long*)(arow + f8 + 4) = pack4bf(xs1);
      *(unsigned long long*)(arow + 64 + f8) = pack4bf(u0);
      *(unsigned long long*)(arow + 64 + f8 + 4) = pack4bf(u1);
    }
  }
  // ---- phase 2: MFMA GEMM on own rows (no barrier needed: A rows self-written) ----
  int l15 = l, q = g;   // same decomposition
  const unsigned short* arow = Asb + (mt * 16 + l15) * ASTR + q * 8;
  f32x4 acc[4] = {{0.f, 0.f, 0.f, 0.f}, {0.f, 0.f, 0.f, 0.f},
                  {0.f, 0.f, 0.f, 0.f}, {0.f, 0.f, 0.f, 0.f}};
#pragma unroll
  for (int ks = 0; ks < 4; ks++) {
    short8 a = *(const short8*)(arow + ks * 32);
#pragma unroll
    for (int nt = 0; nt < 4; nt++) {
      short8 b = *(const short8*)(Wsb + (nt * 16 + l15) * ASTR + ks * 32 + q * 8);
      acc[nt] = __builtin_amdgcn_mfma_f32_16x16x32_bf16(a, b, acc[nt], 0, 0, 0);
    }
  }
  float g_[4], bta[4], wn0[4], wn1[4], tr0[4], tr1[4];
#pragma unroll
  for (int nt = 0; nt < 4; nt++) {
    int f = nt * 16 + l15;
    g_[nt] = ln_g[f]; bta[nt] = ln_b[f];
    wn0[nt] = wa_next[f]; wn1[nt] = wa_next[64 + f];
    tr0[nt] = trt_sh[f]; tr1[nt] = trt_sh[64 + f];
  }
  const float invF = 1.0f / (float)FF;
  float y[4][4];
#pragma unroll
  for (int r = 0; r < 4; r++) {
    int b = r & 1;
    float o[4];
    float s = 0.f, qq = 0.f;
#pragma unroll
    for (int nt = 0; nt < 4; nt++) {
      float v = acc[nt][r] + (b ? tr1[nt] : tr0[nt]);
      o[nt] = v; s += v; qq += v * v;
    }
#pragma unroll
    for (int off = 1; off < 16; off <<= 1) {
      s += __shfl_xor(s, off, 64);
      qq += __shfl_xor(qq, off, 64);
    }
    float mu = s * invF;
    float var = qq * invF - mu * mu;
    float rstd = 1.0f / sqrtf(var + LN_EPS);
    int nl = mt * 8 + q * 2 + (r >> 1);
    size_t base = (size_t)(n0 + nl) * ROW + b * 64 + l15;
#pragma unroll
    for (int nt = 0; nt < 4; nt++) {
      float xo = x_cur[base + nt * 16];
      float on = (o[nt] - mu) * rstd * g_[nt] + bta[nt];
      float h = on > 0.f ? on : expm1f(on);
      float yy = h + xo;
      y[r][nt] = yy;
      x_next[base + nt * 16] = yy;
    }
  }
#pragma unroll
  for (int b = 0; b < 2; b++) {
#pragma unroll
    for (int nt = 0; nt < 4; nt++) {
      atomicAdd(&racc_sh[b * 64 + nt * 16 + l15], y[b][nt] + y[b + 2][nt]);
    }
  }
#pragma unroll
  for (int rp = 0; rp < 2; rp++) {
    float nw = 0.f;
#pragma unroll
    for (int nt = 0; nt < 4; nt++)
      nw += y[2 * rp][nt] * wn0[nt] + y[2 * rp + 1][nt] * wn1[nt];
#pragma unroll
    for (int off = 1; off < 16; off <<= 1) nw += __shfl_xor(nw, off, 64);
    if (l15 == 0) nodewa[n0 + mt * 8 + q * 2 + rp] = nw;
  }
  __syncthreads();
  if (t < 128) atomicAdd(racc_next + t, racc_sh[t]);
}

extern "C" void kernel_launch(void* const* d_in, const int* in_sizes, int n_in,
                              void* d_out, int out_size, void* d_ws, size_t ws_size,
                              hipStream_t stream) {
  const int* ei = (const int*)d_in[0];
  const int* esrc = ei;
  const int* edst = ei + EE;
  const int* rix = (const int*)d_in[1];
  const float* boundary = (const float*)d_in[2];
  const float* query = (const float*)d_in[3];
  const float* rel_w = (const float*)d_in[4];
  const float* rel_b = (const float*)d_in[5];
  const float* layer_w = (const float*)d_in[6];
  const float* layer_b = (const float*)d_in[7];
  const float* tr_w = (const float*)d_in[8];
  const float* tr_b = (const float*)d_in[9];
  const float* Wm = (const float*)d_in[10];
  const float* av = (const float*)d_in[11];
  const float* ln_g = (const float*)d_in[12];
  const float* ln_b = (const float*)d_in[13];
  float* x = (float*)d_out;

  char* ws = (char*)d_ws;
  size_t off = 0;
  auto allocf = [&](size_t n) -> float* {
    float* p = (float*)(ws + off);
    off += ((n * 4 + 255) / 256) * 256;
    return p;
  };
  auto allocu = [&](size_t n) -> unsigned int* {
    unsigned int* p = (unsigned int*)(ws + off);
    off += ((n * 4 + 255) / 256) * 256;
    return p;
  };
  float* relflat = allocf(4096);
  float* wa4 = allocf(512);
  float* alpha_d = allocf(EE);       // alpha in dst-CSR order
  float* xbuf = allocf((size_t)NN * ROW);   // ping-pong partner of d_out
  float* racc0 = allocf(128);
  float* racc1 = allocf(128);
  float* nodewa = allocf(NN);
  unsigned int* hist16 = allocu(H16BINS);
  unsigned int* state = allocu(8);
  unsigned int* deg_s = allocu(NN);
  unsigned int* deg_d = allocu(NN);
  unsigned int* rowptr_s = allocu(NN + 1);
  unsigned int* rowptr_d = allocu(NN + 1);
  unsigned int* rowfill_s = allocu(NN);
  unsigned int* rowfill_d = allocu(NN);
  unsigned int* cspack_s = allocu(EE);
  int* csre_d = (int*)allocu(EE);
  unsigned int* packed_d = allocu(EE);
  unsigned int* pos_d = allocu(EE);
  int* cand_p = (int*)allocu(CCAP);
  float* rbuf[2] = {racc0, racc1};

  hipMemcpyAsync(x, boundary, (size_t)NN * ROW * 4, hipMemcpyDeviceToDevice, stream);
  hipMemsetAsync(deg_s, 0, NN * 4, stream);
  hipMemsetAsync(deg_d, 0, NN * 4, stream);
  hipMemsetAsync(racc0, 0, 128 * 4, stream);
  hipMemsetAsync(hist16, 0, H16BINS * 4, stream);   // once; sel16 self-zeroes per iter
  precompute_kernel<<<16, 256, 0, stream>>>(query, rel_w, rel_b, Wm, av, relflat, wa4);

  // CSR builds (edge_index constant for this launch)
  degcnt_kernel<<<EE / 256, 256, 0, stream>>>(esrc, edst, deg_s, deg_d);
  scan_kernel<<<1, 1024, 0, stream>>>(deg_s, rowptr_s, rowfill_s);
  scan_kernel<<<1, 1024, 0, stream>>>(deg_d, rowptr_d, rowfill_d);
  fill_kernel<<<EE / 256, 256, 0, stream>>>(esrc, edst, rix, rowfill_s, rowfill_d, cspack_s, csre_d);
  gatherd_kernel<<<EE / 256, 256, 0, stream>>>(csre_d, esrc, rix, packed_d, pos_d);
  repack_kernel<<<EE / 256, 256, 0, stream>>>(cspack_s, pos_d);

  // iter-0 readout sum and nodewa (from x = d_out)
  readout_kernel<<<256, 128, 0, stream>>>(x, racc0);
  nodewa_kernel<<<1250, 256, 0, stream>>>(x, wa4, nodewa);

  for (int it = 0; it < 4; it++) {
    float* rcur = rbuf[it & 1];
    float* rnxt = rbuf[(it + 1) & 1];
    const float* wa_it = wa4 + it * 128;
    const float* wa_nx = wa4 + (it < 3 ? it + 1 : 3) * 128;
    float* x_cur = (it & 1) ? xbuf : x;
    float* x_nxt = (it & 1) ? x : xbuf;

    alpha_csr_kernel<<<(NN + 63) / 64, 256, 0, stream>>>(rowptr_s, cspack_s, nodewa,
                                                         relflat, wa_it, alpha_d, hist16, state);
    sel16_kernel<<<1, 1024, 0, stream>>>(state, hist16, rnxt);
    cand_kernel<<<EE / 256, 256, 0, stream>>>(alpha_d, state, cand_p);
    final_kernel<<<1, 256, 0, stream>>>(alpha_d, csre_d, cand_p, state);

    fused_kernel<<<625, 256, 0, stream>>>(rowptr_d, packed_d, alpha_d, state,
                                          x_cur, x_nxt, relflat, layer_w,
                                          rcur, tr_w, tr_b, layer_b, ln_g, ln_b,
                                          wa_nx, nodewa, rnxt);
  }
}